// Round 3
// baseline (346.198 us; speedup 1.0000x reference)
//
#include <hip/hip_runtime.h>
#include <math.h>

// MultiLocalCosineLinear: B=65536 rows, D=768, C=100, P=4950 pairs.
// out layout (all float32): [0..B)  = preds (class id as float)
//                           [B..3B) = logits, row-major (B,2)
//
// R9: pair-grouped pipeline. Theory: the ~120us floor of R0-R8's fused
// kernel is weight traffic — 65536 waves x 6KB random-pair reads = 402 MB
// requested (vs 30 MB of unique weights), flowing through L3/HBM alongside
// the 201 MB x stream. ALU cuts (R8) didn't move it; traffic must.
//   1 norm:      q[t] = sigma[t/2]/||W_t|| (f64)   [+ zero hist]
//   2 topk_hist: per-row DPP top-2 -> packed (a,b), hist[p]++
//   3 scan:      exclusive prefix over 4950 bins (1 block)
//   4 scatter:   slot = atomicAdd(ofs[p]) -> perm[slot] = r|(a<<17)|(b<<24)
//   5 main:      wave i -> row perm[i]; same-pair rows adjacent -> weight
//                tile L2-resident (~13x reuse), r/p SGPR-uniform, no scan.
// Per-row math identical to R8 -> absmax unchanged. All ws buffers fully
// rewritten every launch -> graph-replay safe.

#define D_DIM 768
#define C_DIM 100
#define EPS_N 1e-12

typedef float vf4 __attribute__((ext_vector_type(4)));

// ---- DPP plumbing (all control args compile-time) ----
#define ROW_SHR1    0x111
#define ROW_SHR2    0x112
#define ROW_SHR4    0x114
#define ROW_SHR8    0x118
#define ROW_BCAST15 0x142
#define ROW_BCAST31 0x143

template <int CTRL>
__device__ __forceinline__ float dpp0_f32(float v) {
    return __builtin_bit_cast(float, __builtin_amdgcn_update_dpp(
        0, __builtin_bit_cast(int, v), CTRL, 0xF, 0xF, true));
}

template <int CTRL>
__device__ __forceinline__ double dpp0_f64(double v) {
    union { double d; unsigned long long u; } x; x.d = v;
    int lo = (int)(unsigned int)(x.u & 0xffffffffull);
    int hi = (int)(unsigned int)(x.u >> 32);
    int olo = __builtin_amdgcn_update_dpp(0, lo, CTRL, 0xF, 0xF, true);
    int ohi = __builtin_amdgcn_update_dpp(0, hi, CTRL, 0xF, 0xF, true);
    union { unsigned long long u; double d; } y;
    y.u = ((unsigned long long)(unsigned int)ohi << 32) | (unsigned int)olo;
    return y.d;
}

__device__ __forceinline__ float wave_sum_f32(float v) {
    v += dpp0_f32<ROW_SHR1>(v);
    v += dpp0_f32<ROW_SHR2>(v);
    v += dpp0_f32<ROW_SHR4>(v);
    v += dpp0_f32<ROW_SHR8>(v);
    v += dpp0_f32<ROW_BCAST15>(v);
    v += dpp0_f32<ROW_BCAST31>(v);
    return v;                       // lane 63 holds the full wave sum
}

__device__ __forceinline__ double wave_sum_f64(double v) {
    v += dpp0_f64<ROW_SHR1>(v);
    v += dpp0_f64<ROW_SHR2>(v);
    v += dpp0_f64<ROW_SHR4>(v);
    v += dpp0_f64<ROW_SHR8>(v);
    v += dpp0_f64<ROW_BCAST15>(v);
    v += dpp0_f64<ROW_BCAST31>(v);
    return v;                       // lane 63 holds the full wave sum
}

__device__ __forceinline__ bool vi_gt(float v0, int i0, float v1, int i1) {
    // lexicographic (value desc, index asc) — matches jax.lax.top_k + stable sort
    return (v0 > v1) || (v0 == v1 && i0 < i1);
}

template <int CTRL>
__device__ __forceinline__ void t2_step(float& v1, int& i1, float& v2, int& i2) {
    const int NEGINF = 0xFF800000;       // bits of -inf
    const int BIGIDX = 0x7fffffff;
    float ov1 = __builtin_bit_cast(float, __builtin_amdgcn_update_dpp(
        NEGINF, __builtin_bit_cast(int, v1), CTRL, 0xF, 0xF, false));
    int   oi1 = __builtin_amdgcn_update_dpp(BIGIDX, i1, CTRL, 0xF, 0xF, false);
    float ov2 = __builtin_bit_cast(float, __builtin_amdgcn_update_dpp(
        NEGINF, __builtin_bit_cast(int, v2), CTRL, 0xF, 0xF, false));
    int   oi2 = __builtin_amdgcn_update_dpp(BIGIDX, i2, CTRL, 0xF, 0xF, false);
    if (vi_gt(ov1, oi1, v1, i1)) {
        float nv2; int ni2;
        if (vi_gt(v1, i1, ov2, oi2)) { nv2 = v1;  ni2 = i1; }
        else                         { nv2 = ov2; ni2 = oi2; }
        v1 = ov1; i1 = oi1; v2 = nv2; i2 = ni2;
    } else {
        if (vi_gt(ov1, oi1, v2, i2)) { v2 = ov1; i2 = oi1; }
    }
}

// ---------------------------------------------------------------------------
// 1) per-weight-row q[t] = sigma[t/2]/max(||W_t||,eps) (f64) + zero hist.
// ---------------------------------------------------------------------------
__global__ __launch_bounds__(256) void norm_kernel(
    const float* __restrict__ weights,
    const float* __restrict__ sigma,
    double* __restrict__ q,
    unsigned* __restrict__ hist,
    int P2, int nbins)
{
    const int gid = blockIdx.x * 256 + threadIdx.x;
    if (gid < nbins) hist[gid] = 0u;

    const int lane = threadIdx.x & 63;
    const int t = (blockIdx.x << 2) + (threadIdx.x >> 6);
    if (t >= P2) return;

    const vf4* wv = (const vf4*)(weights + (size_t)t * D_DIM);
    vf4 a0 = wv[lane], a1 = wv[lane + 64], a2 = wv[lane + 128];

    double n = 0.0;
#define SQ(a)                                                                  \
    n += (double)a.x * a.x + (double)a.y * a.y                                 \
       + (double)a.z * a.z + (double)a.w * a.w;
    SQ(a0) SQ(a1) SQ(a2)
#undef SQ
    n = wave_sum_f64(n);
    if (lane == 63) {
        q[t] = (double)sigma[t >> 1] / fmax(sqrt(n), EPS_N);
    }
}

// ---------------------------------------------------------------------------
// 2) per-row top-2 (one wave/row) -> pb[r] = (a<<17)|(b<<24); hist[p]++.
// ---------------------------------------------------------------------------
__global__ __launch_bounds__(256) void topk_hist_kernel(
    const float* __restrict__ first_out,
    unsigned* __restrict__ pb,
    unsigned* __restrict__ hist,
    int B)
{
    const int lane = threadIdx.x & 63;
    const int r = (blockIdx.x << 2) + (threadIdx.x >> 6);
    if (r >= B) return;

    const float* fo = first_out + (size_t)r * C_DIM;
    float e0 = fo[lane];
    int   j1 = lane + 64;
    float e1 = (j1 < C_DIM) ? fo[j1] : -INFINITY;

    float v1, v2; int i1, i2;
    if (vi_gt(e1, j1, e0, lane)) { v1 = e1; i1 = j1;   v2 = e0; i2 = lane; }
    else                         { v1 = e0; i1 = lane; v2 = e1; i2 = j1; }

    t2_step<ROW_SHR1>(v1, i1, v2, i2);
    t2_step<ROW_SHR2>(v1, i1, v2, i2);
    t2_step<ROW_SHR4>(v1, i1, v2, i2);
    t2_step<ROW_SHR8>(v1, i1, v2, i2);
    t2_step<ROW_BCAST15>(v1, i1, v2, i2);
    t2_step<ROW_BCAST31>(v1, i1, v2, i2);

    if (lane == 63) {
        const int a = min(i1, i2);
        const int b = max(i1, i2);
        const int p = b * (b - 1) / 2 + a;
        pb[r] = ((unsigned)a << 17) | ((unsigned)b << 24);
        atomicAdd(&hist[p], 1u);
    }
}

// ---------------------------------------------------------------------------
// 3) exclusive prefix sum over nbins (<= 5120), one block of 1024 threads.
// ---------------------------------------------------------------------------
#define SCAN_T 1024
#define BINS_PER_T 5
__global__ __launch_bounds__(SCAN_T) void scan_kernel(
    const unsigned* __restrict__ hist,
    unsigned* __restrict__ ofs,
    int nbins)
{
    __shared__ unsigned lds[SCAN_T];
    const int t = threadIdx.x;
    unsigned loc[BINS_PER_T];
    unsigned s = 0;
#pragma unroll
    for (int k = 0; k < BINS_PER_T; ++k) {
        int idx = t * BINS_PER_T + k;
        unsigned v = (idx < nbins) ? hist[idx] : 0u;
        loc[k] = s;                 // thread-local exclusive prefix
        s += v;
    }
    lds[t] = s;
    __syncthreads();
    for (int d = 1; d < SCAN_T; d <<= 1) {
        unsigned v = (t >= d) ? lds[t - d] : 0u;
        __syncthreads();
        lds[t] += v;
        __syncthreads();
    }
    unsigned base = (t > 0) ? lds[t - 1] : 0u;   // exclusive of this thread
#pragma unroll
    for (int k = 0; k < BINS_PER_T; ++k) {
        int idx = t * BINS_PER_T + k;
        if (idx < nbins) ofs[idx] = base + loc[k];
    }
}

// ---------------------------------------------------------------------------
// 4) scatter rows into pair-major order: perm[slot] = r | pb[r].
// ---------------------------------------------------------------------------
__global__ __launch_bounds__(256) void scatter_kernel(
    const unsigned* __restrict__ pb,
    unsigned* __restrict__ ofs,
    unsigned* __restrict__ perm,
    int B)
{
    const int r = blockIdx.x * 256 + threadIdx.x;
    if (r >= B) return;
    const unsigned v = pb[r];
    const int a = (int)((v >> 17) & 0x7f);
    const int b = (int)((v >> 24) & 0x7f);
    const int p = b * (b - 1) / 2 + a;
    const unsigned slot = atomicAdd(&ofs[p], 1u);
    perm[slot] = v | (unsigned)r;
}

// ---------------------------------------------------------------------------
// 5) main: wave i -> row perm[i]. r, a, b, p all SGPR-uniform. No scan.
// ---------------------------------------------------------------------------
__global__ __launch_bounds__(256) void mlcl_main(
    const float* __restrict__ x,
    const float* __restrict__ weights,
    const double* __restrict__ q,
    const unsigned* __restrict__ perm,
    float* __restrict__ out,
    int B)
{
    const int lane = threadIdx.x & 63;
    const int i = (blockIdx.x << 2) + (threadIdx.x >> 6);
    if (i >= B) return;

    const int e = __builtin_amdgcn_readfirstlane((int)perm[i]);
    const int r = e & 0x1ffff;
    const int a = (e >> 17) & 0x7f;
    const int b = (e >> 24) & 0x7f;
    const int p = b * (b - 1) / 2 + a;

    // uniform p -> scalar loads for q, scalar base for weights
    const double q0 = q[2 * (size_t)p];
    const double q1 = q[2 * (size_t)p + 1];

    const vf4* xv = (const vf4*)(x + (size_t)r * D_DIM);
    vf4 xa0 = xv[lane], xa1 = xv[lane + 64], xa2 = xv[lane + 128];

    const vf4* wv = (const vf4*)(weights + (size_t)p * (2 * D_DIM));
    vf4 w00 = wv[lane],       w01 = wv[lane + 64],       w02 = wv[lane + 128];
    vf4 w10 = wv[192 + lane], w11 = wv[192 + lane + 64], w12 = wv[192 + lane + 128];

    float  xx = 0.f;                 // common positive scale — f32 ok
    double d0 = 0.0, d1 = 0.0;       // feed argmax — f64
#define ACC(xa, w0, w1)                                                       \
    xx += xa.x * xa.x + xa.y * xa.y + xa.z * xa.z + xa.w * xa.w;              \
    d0 += (double)xa.x * w0.x + (double)xa.y * w0.y                           \
        + (double)xa.z * w0.z + (double)xa.w * w0.w;                          \
    d1 += (double)xa.x * w1.x + (double)xa.y * w1.y                           \
        + (double)xa.z * w1.z + (double)xa.w * w1.w;
    ACC(xa0, w00, w10)
    ACC(xa1, w01, w11)
    ACC(xa2, w02, w12)
#undef ACC

    xx = wave_sum_f32(xx);
    d0 = wave_sum_f64(d0);
    d1 = wave_sum_f64(d1);

    if (lane == 63) {
        const double inx = 1.0 / fmax(sqrt((double)xx), EPS_N);
        const double l0  = q0 * d0 * inx;
        const double l1  = q1 * d1 * inx;
        const int sel = (l1 > l0) ? 1 : 0;   // jnp.argmax: first index wins ties
        out[r] = (float)(sel ? b : a);
        float2 lg = make_float2((float)l0, (float)l1);
        *(float2*)(out + B + 2 * (size_t)r) = lg;    // 8B-aligned: B even
    }
}

extern "C" void kernel_launch(void* const* d_in, const int* in_sizes, int n_in,
                              void* d_out, int out_size, void* d_ws, size_t ws_size,
                              hipStream_t stream) {
    const float* x         = (const float*)d_in[0];
    const float* first_out = (const float*)d_in[1];
    const float* weights   = (const float*)d_in[2];
    const float* sigma     = (const float*)d_in[3];
    float* out = (float*)d_out;

    const int B  = in_sizes[0] / D_DIM;    // 65536
    const int P2 = in_sizes[2] / D_DIM;    // 2*P = 9900
    const int NB = P2 / 2;                 // 4950 pairs

    // ws layout (all 256B-aligned)
    char* ws = (char*)d_ws;
    size_t o = 0;
    double*   q    = (double*)(ws + o);  o += ((size_t)P2 * 8 + 255) & ~255ull;
    unsigned* hist = (unsigned*)(ws + o); o += ((size_t)NB * 4 + 255) & ~255ull;
    unsigned* ofs  = (unsigned*)(ws + o); o += ((size_t)NB * 4 + 255) & ~255ull;
    unsigned* pb   = (unsigned*)(ws + o); o += ((size_t)B * 4 + 255) & ~255ull;
    unsigned* perm = (unsigned*)(ws + o);

    hipLaunchKernelGGL(norm_kernel, dim3((P2 + 3) / 4), dim3(256), 0, stream,
                       weights, sigma, q, hist, P2, NB);
    hipLaunchKernelGGL(topk_hist_kernel, dim3((B + 3) / 4), dim3(256), 0, stream,
                       first_out, pb, hist, B);
    hipLaunchKernelGGL(scan_kernel, dim3(1), dim3(SCAN_T), 0, stream,
                       hist, ofs, NB);
    hipLaunchKernelGGL(scatter_kernel, dim3((B + 255) / 256), dim3(256), 0, stream,
                       pb, ofs, perm, B);
    hipLaunchKernelGGL(mlcl_main, dim3((B + 3) / 4), dim3(256), 0, stream,
                       x, weights, q, perm, out, B);
}